// Round 6
// baseline (292.242 us; speedup 1.0000x reference)
//
#include <hip/hip_runtime.h>
#include <math.h>

#define B_ 2
#define S_ 2048
#define D_ 1024
#define H_ 16
#define HD_ 64

typedef __bf16 bf16;
typedef bf16 bf16x8_t __attribute__((ext_vector_type(8)));
typedef short s16x8 __attribute__((ext_vector_type(8)));
typedef float f32x4 __attribute__((ext_vector_type(4)));

static __device__ __forceinline__ f32x4 mfma16(s16x8 a, s16x8 b, f32x4 c) {
  return __builtin_amdgcn_mfma_f32_16x16x32_bf16(a, b, c, 0, 0, 0);
}

static __device__ __forceinline__ s16x8 cvt2x4(f32x4 a, f32x4 b) {
  bf16x8_t t;
  t[0] = (bf16)a[0]; t[1] = (bf16)a[1]; t[2] = (bf16)a[2]; t[3] = (bf16)a[3];
  t[4] = (bf16)b[0]; t[5] = (bf16)b[1]; t[6] = (bf16)b[2]; t[7] = (bf16)b[3];
  return __builtin_bit_cast(s16x8, t);
}

// async global->LDS, 16B/lane; LDS dest is wave-uniform base (HW adds lane*16)
static __device__ __forceinline__ void gl16(const bf16* g, bf16* l) {
  __builtin_amdgcn_global_load_lds((const __attribute__((address_space(1))) void*)g,
                                   (__attribute__((address_space(3))) void*)l, 16, 0, 0);
}

// drain all outstanding vm+lds ops, then raw barrier (2-phase pipeline fence)
static __device__ __forceinline__ void fence_barrier() {
  asm volatile("s_waitcnt vmcnt(0) lgkmcnt(0)" ::: "memory");
  __builtin_amdgcn_s_barrier();
  asm volatile("" ::: "memory");
}

// fp32 -> bf16 for the 3 QKV weight matrices (each D*D)
__global__ __launch_bounds__(256) void cvt_w(
    const float* __restrict__ Wq, const float* __restrict__ Wk,
    const float* __restrict__ Wv, bf16* __restrict__ dst) {
  const float* s = blockIdx.y == 0 ? Wq : (blockIdx.y == 1 ? Wk : Wv);
  bf16* d = dst + (size_t)blockIdx.y * D_ * D_;
  const int i = (blockIdx.x * 256 + threadIdx.x) * 8;
  f32x4 a = *(const f32x4*)(s + i);
  f32x4 b = *(const f32x4*)(s + i + 4);
  *(s16x8*)(d + i) = cvt2x4(a, b);
}

// fp32 -> bf16 single matrix (Wo)
__global__ __launch_bounds__(256) void cvt_w1(
    const float* __restrict__ W, bf16* __restrict__ dst) {
  const int i = (blockIdx.x * 256 + threadIdx.x) * 8;
  f32x4 a = *(const f32x4*)(W + i);
  f32x4 b = *(const f32x4*)(W + i + 4);
  *(s16x8*)(dst + i) = cvt2x4(a, b);
}

// Fused QKV projection: X(fp32) @ W^T + b. BK=64, 2-phase double-buffered pipeline.
// wsel: 0=Q (scaled, [bh][s][hd]), 1=K ([bh][s][hd]), 2=V ([bh][hd][s]).
__global__ __launch_bounds__(256) void qkv_gemm(
    const float* __restrict__ q, const float* __restrict__ k, const float* __restrict__ v,
    const bf16* __restrict__ Wb,
    const float* __restrict__ bq, const float* __restrict__ bk, const float* __restrict__ bv,
    bf16* __restrict__ Qh, bf16* __restrict__ Kh, bf16* __restrict__ Vt) {
  __shared__ bf16 lA[2][128][72];   // reg-staged fp32->bf16, padded
  __shared__ bf16 lB[2][128][64];   // gl16, source chunk-swizzled
  const int tid = threadIdx.x, lane = tid & 63, wave = tid >> 6;
  const int wsel = blockIdx.y >> 3;
  const int col0 = (blockIdx.y & 7) * 128;
  const int row0 = blockIdx.x * 128;
  const float* X = wsel == 0 ? q : (wsel == 1 ? k : v);
  const bf16* W = Wb + (size_t)wsel * D_ * D_;
  const float* bias = wsel == 0 ? bq : (wsel == 1 ? bk : bv);

  const int lr = lane & 15, g = lane >> 4, lk = g * 8;
  const int wrow = (wave >> 1) * 64, wcol = (wave & 1) * 64;

  const int arow = tid >> 1, aseg = (tid & 1) * 32;
  const float* Xp = X + (size_t)(row0 + arow) * D_ + aseg;

  const bf16* Wp = W + (size_t)(col0 + wave * 32 + (lane >> 3)) * D_ +
                   (size_t)(((lane & 7) ^ ((lane >> 3) & 7)) * 8);

  f32x4 acc[4][4] = {};
  f32x4 xr[8];

  // ---- prologue: stage tile 0, prefetch X tile 1 ----
#pragma unroll
  for (int j = 0; j < 8; j++) xr[j] = *(const f32x4*)(Xp + j * 4);
#pragma unroll
  for (int i = 0; i < 4; i++) gl16(Wp + (size_t)i * 8 * D_, &lB[0][wave * 32][0] + i * 8 * 64);
#pragma unroll
  for (int p = 0; p < 4; p++)
    *(s16x8*)&lA[0][arow][aseg + p * 8] = cvt2x4(xr[2 * p], xr[2 * p + 1]);
#pragma unroll
  for (int j = 0; j < 8; j++) xr[j] = *(const f32x4*)(Xp + 64 + j * 4);
  fence_barrier();

  const int NT = D_ / 64;  // 16
  for (int t = 0; t < NT; t++) {
    const int cur = t & 1;
    if (t + 1 < NT) {
      // stage tile t+1 into the other buffer; lands during this tile's MFMA
#pragma unroll
      for (int i = 0; i < 4; i++)
        gl16(Wp + (size_t)i * 8 * D_ + (t + 1) * 64, &lB[cur ^ 1][wave * 32][0] + i * 8 * 64);
#pragma unroll
      for (int p = 0; p < 4; p++)
        *(s16x8*)&lA[cur ^ 1][arow][aseg + p * 8] = cvt2x4(xr[2 * p], xr[2 * p + 1]);
      if (t + 2 < NT) {
#pragma unroll
        for (int j = 0; j < 8; j++) xr[j] = *(const f32x4*)(Xp + (t + 2) * 64 + j * 4);
      }
    }

    s16x8 af[4][2], bfr[4][2];
#pragma unroll
    for (int mi = 0; mi < 4; mi++)
#pragma unroll
      for (int kd = 0; kd < 2; kd++)
        af[mi][kd] = *(const s16x8*)&lA[cur][wrow + mi * 16 + lr][kd * 32 + lk];
#pragma unroll
    for (int ni = 0; ni < 4; ni++)
#pragma unroll
      for (int kd = 0; kd < 2; kd++)
        bfr[ni][kd] = *(const s16x8*)((const bf16*)lB + (size_t)cur * 128 * 64 +
                        (size_t)(wcol + ni * 16 + lr) * 64 +
                        (((4 * kd + g) ^ (lr & 7)) * 8));
    __builtin_amdgcn_s_setprio(1);
#pragma unroll
    for (int mi = 0; mi < 4; mi++)
#pragma unroll
      for (int ni = 0; ni < 4; ni++)
#pragma unroll
        for (int kd = 0; kd < 2; kd++)
          acc[mi][ni] = mfma16(af[mi][kd], bfr[ni][kd], acc[mi][ni]);
    __builtin_amdgcn_s_setprio(0);
    if (t + 1 < NT) fence_barrier();
  }

  const int rb = g * 4;
#pragma unroll
  for (int mi = 0; mi < 4; mi++) {
#pragma unroll
    for (int ni = 0; ni < 4; ni++) {
      const int col = col0 + wcol + ni * 16 + lr;
      const int h = col >> 6, hd = col & 63;
      const float bvv = bias[col];
#pragma unroll
      for (int r = 0; r < 4; r++) {
        const int row = row0 + wrow + mi * 16 + rb + r;
        const int b = row >> 11, s = row & (S_ - 1);
        const float val = acc[mi][ni][r] + bvv;
        if (wsel == 0)
          Qh[(((size_t)(b * H_ + h)) * S_ + s) * HD_ + hd] = (bf16)(val * 0.125f);
        else if (wsel == 1)
          Kh[(((size_t)(b * H_ + h)) * S_ + s) * HD_ + hd] = (bf16)val;
        else
          Vt[(((size_t)(b * H_ + h)) * HD_ + hd) * S_ + s] = (bf16)val;
      }
    }
  }
}

// out = X(bf16) @ Wo_b^T + bias, fp32 out [4096][1024]. 64x128 tiles, BK=64,
// 2-phase double-buffered gl16 pipeline.
__global__ __launch_bounds__(256) void out_gemm(
    const bf16* __restrict__ X, const bf16* __restrict__ W,
    const float* __restrict__ bias, float* __restrict__ Y) {
  __shared__ bf16 lA[2][64][64];
  __shared__ bf16 lB[2][128][64];
  const int tid = threadIdx.x, lane = tid & 63, wave = tid >> 6;
  const int row0 = blockIdx.x * 64, col0 = blockIdx.y * 128;
  const int lr = lane & 15, g = lane >> 4, lk = g * 8;
  const int wrow = (wave >> 1) * 32, wcol = (wave & 1) * 64;
  const int csw = ((lane & 7) ^ ((lane >> 3) & 7)) * 8;

  const bf16* Ap = X + (size_t)(row0 + wave * 16 + (lane >> 3)) * D_ + csw;
  const bf16* Wp = W + (size_t)(col0 + wave * 32 + (lane >> 3)) * D_ + csw;

  f32x4 acc[2][4] = {};

  // prologue: stage tile 0
#pragma unroll
  for (int i = 0; i < 2; i++) gl16(Ap + (size_t)i * 8 * D_, &lA[0][wave * 16][0] + i * 8 * 64);
#pragma unroll
  for (int i = 0; i < 4; i++) gl16(Wp + (size_t)i * 8 * D_, &lB[0][wave * 32][0] + i * 8 * 64);
  fence_barrier();

  const int NT = D_ / 64;
  for (int t = 0; t < NT; t++) {
    const int cur = t & 1;
    if (t + 1 < NT) {
      const int kk = (t + 1) * 64;
#pragma unroll
      for (int i = 0; i < 2; i++)
        gl16(Ap + (size_t)i * 8 * D_ + kk, &lA[cur ^ 1][wave * 16][0] + i * 8 * 64);
#pragma unroll
      for (int i = 0; i < 4; i++)
        gl16(Wp + (size_t)i * 8 * D_ + kk, &lB[cur ^ 1][wave * 32][0] + i * 8 * 64);
    }

    s16x8 af[2][2], bfr[4][2];
#pragma unroll
    for (int mi = 0; mi < 2; mi++)
#pragma unroll
      for (int kd = 0; kd < 2; kd++)
        af[mi][kd] = *(const s16x8*)((const bf16*)lA + (size_t)cur * 64 * 64 +
                       (size_t)(wrow + mi * 16 + lr) * 64 +
                       (((4 * kd + g) ^ (lr & 7)) * 8));
#pragma unroll
    for (int ni = 0; ni < 4; ni++)
#pragma unroll
      for (int kd = 0; kd < 2; kd++)
        bfr[ni][kd] = *(const s16x8*)((const bf16*)lB + (size_t)cur * 128 * 64 +
                        (size_t)(wcol + ni * 16 + lr) * 64 +
                        (((4 * kd + g) ^ (lr & 7)) * 8));
    __builtin_amdgcn_s_setprio(1);
#pragma unroll
    for (int mi = 0; mi < 2; mi++)
#pragma unroll
      for (int ni = 0; ni < 4; ni++)
#pragma unroll
        for (int kd = 0; kd < 2; kd++)
          acc[mi][ni] = mfma16(af[mi][kd], bfr[ni][kd], acc[mi][ni]);
    __builtin_amdgcn_s_setprio(0);
    if (t + 1 < NT) fence_barrier();
  }

  const int rb = g * 4;
#pragma unroll
  for (int mi = 0; mi < 2; mi++) {
#pragma unroll
    for (int ni = 0; ni < 4; ni++) {
      const int col = col0 + wcol + ni * 16 + lr;
      const float bvv = bias[col];
#pragma unroll
      for (int r = 0; r < 4; r++) {
        const int row = row0 + wrow + mi * 16 + rb + r;
        Y[(size_t)row * D_ + col] = acc[mi][ni][r] + bvv;
      }
    }
  }
}

// Causal flash attention, swapped-QK^T softmax (col=q -> 2 shuffles/row-reduce).
// Qh/Kh: [bh][S][HD] bf16 (Q pre-scaled), Vt: [bh][HD][S] bf16. Out: [B*S][D] bf16.
__global__ __launch_bounds__(256) void attn_fwd(
    const bf16* __restrict__ Qh, const bf16* __restrict__ Kh,
    const bf16* __restrict__ Vt, bf16* __restrict__ attnO) {
  __shared__ bf16 k_lds[64][72];
  __shared__ bf16 vt_lds[64][72];
  __shared__ bf16 p_lds[4][32][72];
  __shared__ float red_lds[4][32];

  const int tid = threadIdx.x;
  const int lane = tid & 63, wave = tid >> 6;
  const int lr = lane & 15, g = lane >> 4, lk = g * 8, rb = g * 4;

  const int bidx = blockIdx.x;        // 512 blocks
  const int qb = 15 - (bidx >> 5);    // longest-first
  const int bh = bidx & 31;
  const int bb = bh >> 4, hh = bh & 15;
  const int q0w = qb * 128 + wave * 32;

  const bf16* Q = Qh + (size_t)bh * S_ * HD_;
  const bf16* K = Kh + (size_t)bh * S_ * HD_;
  const bf16* Vp = Vt + (size_t)bh * HD_ * S_;

  s16x8 qf[2][2];
#pragma unroll
  for (int qfi = 0; qfi < 2; qfi++)
#pragma unroll
    for (int kd = 0; kd < 2; kd++)
      qf[qfi][kd] = *(const s16x8*)(Q + (size_t)(q0w + qfi * 16 + lr) * HD_ + kd * 32 + lk);

  f32x4 o[2][4] = {};
  float m_run[2] = {-INFINITY, -INFINITY};
  float l_run[2] = {0.0f, 0.0f};

  const int srow = tid >> 2, d0 = (tid & 3) << 4;
  const int ntiles = qb * 2 + 2;

  s16x8 kr0, kr1, vr0, vr1;
  {
    const bf16* kp = K + (size_t)srow * HD_ + d0;
    kr0 = *(const s16x8*)kp;
    kr1 = *(const s16x8*)(kp + 8);
    const bf16* vp = Vp + (size_t)srow * S_ + d0;
    vr0 = *(const s16x8*)vp;
    vr1 = *(const s16x8*)(vp + 8);
  }

  for (int t = 0; t < ntiles; t++) {
    const int k0 = t * 64;
    __syncthreads();
    *(s16x8*)&k_lds[srow][d0] = kr0;
    *(s16x8*)&k_lds[srow][d0 + 8] = kr1;
    *(s16x8*)&vt_lds[srow][d0] = vr0;
    *(s16x8*)&vt_lds[srow][d0 + 8] = vr1;
    __syncthreads();
    if (t + 1 < ntiles) {
      const int kn = k0 + 64;
      const bf16* kp = K + (size_t)(kn + srow) * HD_ + d0;
      kr0 = *(const s16x8*)kp;
      kr1 = *(const s16x8*)(kp + 8);
      const bf16* vp = Vp + (size_t)srow * S_ + kn + d0;
      vr0 = *(const s16x8*)vp;
      vr1 = *(const s16x8*)(vp + 8);
    }

    if (k0 <= q0w + 31) {
      const bool doMask = (k0 + 63 > q0w);
      s16x8 kfr[4][2];
#pragma unroll
      for (int kf = 0; kf < 4; kf++)
#pragma unroll
        for (int kd = 0; kd < 2; kd++)
          kfr[kf][kd] = *(const s16x8*)&k_lds[kf * 16 + lr][kd * 32 + lk];
      f32x4 s[4][2];
#pragma unroll
      for (int kf = 0; kf < 4; kf++)
#pragma unroll
        for (int qfi = 0; qfi < 2; qfi++) s[kf][qfi] = (f32x4){0.f, 0.f, 0.f, 0.f};
      __builtin_amdgcn_s_setprio(1);
#pragma unroll
      for (int kf = 0; kf < 4; kf++)
#pragma unroll
        for (int qfi = 0; qfi < 2; qfi++)
#pragma unroll
          for (int kd = 0; kd < 2; kd++)
            s[kf][qfi] = mfma16(kfr[kf][kd], qf[qfi][kd], s[kf][qfi]);
      __builtin_amdgcn_s_setprio(0);

#pragma unroll
      for (int qfi = 0; qfi < 2; qfi++) {
        const int qg = q0w + qfi * 16 + lr;
        if (doMask) {
#pragma unroll
          for (int kf = 0; kf < 4; kf++)
#pragma unroll
            for (int r = 0; r < 4; r++)
              if (k0 + kf * 16 + rb + r > qg) s[kf][qfi][r] = -INFINITY;
        }
        float mx = fmaxf(fmaxf(s[0][qfi][0], s[0][qfi][1]), fmaxf(s[0][qfi][2], s[0][qfi][3]));
#pragma unroll
        for (int kf = 1; kf < 4; kf++)
          mx = fmaxf(mx, fmaxf(fmaxf(s[kf][qfi][0], s[kf][qfi][1]),
                               fmaxf(s[kf][qfi][2], s[kf][qfi][3])));
        mx = fmaxf(mx, __shfl_xor(mx, 16));
        mx = fmaxf(mx, __shfl_xor(mx, 32));
        const float mo = m_run[qfi];
        const float mn = fmaxf(mo, mx);
        const float corr = exp2f((mo - mn) * 1.44269504f);
        float ps = 0.0f;
#pragma unroll
        for (int kf = 0; kf < 4; kf++)
#pragma unroll
          for (int r = 0; r < 4; r++) {
            const float p = exp2f((s[kf][qfi][r] - mn) * 1.44269504f);
            s[kf][qfi][r] = p;
            ps += p;
          }
        ps += __shfl_xor(ps, 16);
        ps += __shfl_xor(ps, 32);
        l_run[qfi] = l_run[qfi] * corr + ps;
        m_run[qfi] = mn;
        if (g == 0) red_lds[wave][qfi * 16 + lr] = corr;
#pragma unroll
        for (int kf = 0; kf < 4; kf++)
#pragma unroll
          for (int rp = 0; rp < 2; rp++) {
            unsigned int lo = (unsigned int)__builtin_bit_cast(
                unsigned short, (bf16)s[kf][qfi][2 * rp]);
            unsigned int hi = (unsigned int)__builtin_bit_cast(
                unsigned short, (bf16)s[kf][qfi][2 * rp + 1]);
            *(unsigned int*)&p_lds[wave][qfi * 16 + lr][kf * 16 + rb + 2 * rp] =
                lo | (hi << 16);
          }
      }
#pragma unroll
      for (int rf = 0; rf < 2; rf++) {
        f32x4 c4 = *(const f32x4*)&red_lds[wave][rf * 16 + rb];
#pragma unroll
        for (int df = 0; df < 4; df++)
#pragma unroll
          for (int r = 0; r < 4; r++) o[rf][df][r] *= c4[r];
      }
      s16x8 vfr[4][2];
#pragma unroll
      for (int df = 0; df < 4; df++)
#pragma unroll
        for (int kk = 0; kk < 2; kk++)
          vfr[df][kk] = *(const s16x8*)&vt_lds[df * 16 + lr][kk * 32 + lk];
      __builtin_amdgcn_s_setprio(1);
#pragma unroll
      for (int rf = 0; rf < 2; rf++) {
        s16x8 pa[2];
#pragma unroll
        for (int kk = 0; kk < 2; kk++)
          pa[kk] = *(const s16x8*)&p_lds[wave][rf * 16 + lr][kk * 32 + lk];
#pragma unroll
        for (int df = 0; df < 4; df++)
#pragma unroll
          for (int kk = 0; kk < 2; kk++)
            o[rf][df] = mfma16(pa[kk], vfr[df][kk], o[rf][df]);
      }
      __builtin_amdgcn_s_setprio(0);
    }
  }

  if (g == 0) {
    red_lds[wave][lr] = l_run[0];
    red_lds[wave][16 + lr] = l_run[1];
  }
#pragma unroll
  for (int rf = 0; rf < 2; rf++) {
    f32x4 l4 = *(const f32x4*)&red_lds[wave][rf * 16 + rb];
    float inv[4];
#pragma unroll
    for (int r = 0; r < 4; r++) inv[r] = 1.0f / l4[r];
#pragma unroll
    for (int df = 0; df < 4; df++)
#pragma unroll
      for (int r = 0; r < 4; r++) {
        const int srw = q0w + rf * 16 + rb + r;
        const int dcol = df * 16 + lr;
        attnO[((size_t)(bb * S_ + srw)) * D_ + hh * HD_ + dcol] =
            (bf16)(o[rf][df][r] * inv[r]);
      }
  }
}

extern "C" void kernel_launch(void* const* d_in, const int* in_sizes, int n_in,
                              void* d_out, int out_size, void* d_ws, size_t ws_size,
                              hipStream_t stream) {
  const float* q  = (const float*)d_in[0];
  const float* k  = (const float*)d_in[1];
  const float* v  = (const float*)d_in[2];
  const float* Wq = (const float*)d_in[4];
  const float* bq = (const float*)d_in[5];
  const float* Wk = (const float*)d_in[6];
  const float* bk = (const float*)d_in[7];
  const float* Wv = (const float*)d_in[8];
  const float* bv = (const float*)d_in[9];
  const float* Wo = (const float*)d_in[10];
  const float* bo = (const float*)d_in[11];
  float* out = (float*)d_out;

  // 32 MB workspace layout (proven safe):
  //   [0,8M)   Qh     [8M,16M) Kh     [16M,24M) Vt
  //   [24M,30M) Wq_b|Wk_b|Wv_b (consumed by qkv_gemm)
  //   [24M,32M) attnB (reuses weight region after qkv_gemm — stream-ordered)
  //   [0,2M)    Wo_b  (reuses Qh region after attn_fwd — stream-ordered)
  const size_t NE = (size_t)B_ * S_ * D_;
  bf16* Qh    = (bf16*)d_ws;
  bf16* Kh    = Qh + NE;
  bf16* Vt    = Kh + NE;
  bf16* WbQKV = Vt + NE;
  bf16* attnB = Vt + NE;
  bf16* WoB   = (bf16*)d_ws;

  cvt_w<<<dim3(512, 3), 256, 0, stream>>>(Wq, Wk, Wv, WbQKV);
  qkv_gemm<<<dim3(32, 24), 256, 0, stream>>>(q, k, v, WbQKV, bq, bk, bv, Qh, Kh, Vt);
  attn_fwd<<<512, 256, 0, stream>>>(Qh, Kh, Vt, attnB);
  cvt_w1<<<512, 256, 0, stream>>>(Wo, WoB);
  out_gemm<<<dim3(64, 8), 256, 0, stream>>>(attnB, WoB, bo, out);
}

// Round 8
// 272.542 us; speedup vs baseline: 1.0723x; 1.0723x over previous
//
#include <hip/hip_runtime.h>
#include <math.h>

#define B_ 2
#define S_ 2048
#define D_ 1024
#define H_ 16
#define HD_ 64

typedef __bf16 bf16;
typedef bf16 bf16x8_t __attribute__((ext_vector_type(8)));
typedef short s16x8 __attribute__((ext_vector_type(8)));
typedef float f32x4 __attribute__((ext_vector_type(4)));

static __device__ __forceinline__ f32x4 mfma16(s16x8 a, s16x8 b, f32x4 c) {
  return __builtin_amdgcn_mfma_f32_16x16x32_bf16(a, b, c, 0, 0, 0);
}

static __device__ __forceinline__ s16x8 cvt2x4(f32x4 a, f32x4 b) {
  bf16x8_t t;
  t[0] = (bf16)a[0]; t[1] = (bf16)a[1]; t[2] = (bf16)a[2]; t[3] = (bf16)a[3];
  t[4] = (bf16)b[0]; t[5] = (bf16)b[1]; t[6] = (bf16)b[2]; t[7] = (bf16)b[3];
  return __builtin_bit_cast(s16x8, t);
}

// async global->LDS, 16B/lane; LDS dest is wave-uniform base (HW adds lane*16)
static __device__ __forceinline__ void gl16(const bf16* g, bf16* l) {
  __builtin_amdgcn_global_load_lds((const __attribute__((address_space(1))) void*)g,
                                   (__attribute__((address_space(3))) void*)l, 16, 0, 0);
}

// fp32 -> bf16 for the 3 QKV weight matrices (each D*D)
__global__ __launch_bounds__(256) void cvt_w(
    const float* __restrict__ Wq, const float* __restrict__ Wk,
    const float* __restrict__ Wv, bf16* __restrict__ dst) {
  const float* s = blockIdx.y == 0 ? Wq : (blockIdx.y == 1 ? Wk : Wv);
  bf16* d = dst + (size_t)blockIdx.y * D_ * D_;
  const int i = (blockIdx.x * 256 + threadIdx.x) * 8;
  f32x4 a = *(const f32x4*)(s + i);
  f32x4 b = *(const f32x4*)(s + i + 4);
  *(s16x8*)(d + i) = cvt2x4(a, b);
}

// fp32 -> bf16 single matrix (Wo)
__global__ __launch_bounds__(256) void cvt_w1(
    const float* __restrict__ W, bf16* __restrict__ dst) {
  const int i = (blockIdx.x * 256 + threadIdx.x) * 8;
  f32x4 a = *(const f32x4*)(W + i);
  f32x4 b = *(const f32x4*)(W + i + 4);
  *(s16x8*)(dst + i) = cvt2x4(a, b);
}

// Fused QKV projection: X(fp32) @ W^T + b. 128x256 tile, 8 waves, BK=64.
// wsel: 0=Q (scaled, [bh][s][hd]), 1=K ([bh][s][hd]), 2=V ([bh][hd][s]).
__global__ __launch_bounds__(512, 4) void qkv_gemm(
    const float* __restrict__ q, const float* __restrict__ k, const float* __restrict__ v,
    const bf16* __restrict__ Wb,
    const float* __restrict__ bq, const float* __restrict__ bk, const float* __restrict__ bv,
    bf16* __restrict__ Qh, bf16* __restrict__ Kh, bf16* __restrict__ Vt) {
  __shared__ bf16 lA[128][72];   // reg-staged fp32->bf16, padded
  __shared__ bf16 lB[256][64];   // gl16, source chunk-swizzled
  const int tid = threadIdx.x, lane = tid & 63, wave = tid >> 6;
  const int wsel = blockIdx.y >> 2;
  const int col0 = (blockIdx.y & 3) * 256;
  const int row0 = blockIdx.x * 128;
  const float* X = wsel == 0 ? q : (wsel == 1 ? k : v);
  const bf16* W = Wb + (size_t)wsel * D_ * D_;
  const float* bias = wsel == 0 ? bq : (wsel == 1 ? bk : bv);

  const int lr = lane & 15, g = lane >> 4, lk = g * 8;
  const int wrow = (wave >> 2) * 64, wcol = (wave & 3) * 64;

  // A staging: 4 threads per row, each 16 fp32 cols
  const int arow = tid >> 2, aseg = (tid & 3) * 16;
  const float* Xp = X + (size_t)(row0 + arow) * D_ + aseg;

  // B staging via gl16 with source chunk swizzle
  const bf16* Wp = W + (size_t)(col0 + wave * 32 + (lane >> 3)) * D_ +
                   (size_t)(((lane & 7) ^ ((lane >> 3) & 7)) * 8);
  bf16* lBw = &lB[wave * 32][0];

  f32x4 acc[4][4] = {};
  f32x4 xr[4];
#pragma unroll
  for (int j = 0; j < 4; j++) xr[j] = *(const f32x4*)(Xp + j * 4);

  for (int kk = 0; kk < D_; kk += 64) {
    __syncthreads();  // previous iter's LDS reads complete
    *(s16x8*)&lA[arow][aseg] = cvt2x4(xr[0], xr[1]);
    *(s16x8*)&lA[arow][aseg + 8] = cvt2x4(xr[2], xr[3]);
#pragma unroll
    for (int i = 0; i < 4; i++)
      gl16(Wp + (size_t)i * 8 * D_ + kk, lBw + i * 8 * 64);
    __syncthreads();  // staging drained (compiler inserts waitcnts)
    if (kk + 64 < D_) {
#pragma unroll
      for (int j = 0; j < 4; j++) xr[j] = *(const f32x4*)(Xp + kk + 64 + j * 4);
    }

#pragma unroll
    for (int kd = 0; kd < 2; kd++) {
      s16x8 af[4], bfr[4];
#pragma unroll
      for (int mi = 0; mi < 4; mi++)
        af[mi] = *(const s16x8*)&lA[wrow + mi * 16 + lr][kd * 32 + lk];
#pragma unroll
      for (int ni = 0; ni < 4; ni++)
        bfr[ni] = *(const s16x8*)((const bf16*)lB +
                    (size_t)(wcol + ni * 16 + lr) * 64 +
                    (((4 * kd + g) ^ (lr & 7)) * 8));
#pragma unroll
      for (int mi = 0; mi < 4; mi++)
#pragma unroll
        for (int ni = 0; ni < 4; ni++)
          acc[mi][ni] = mfma16(af[mi], bfr[ni], acc[mi][ni]);
    }
  }

  const int rb = g * 4;
#pragma unroll
  for (int mi = 0; mi < 4; mi++) {
#pragma unroll
    for (int ni = 0; ni < 4; ni++) {
      const int col = col0 + wcol + ni * 16 + lr;
      const int h = col >> 6, hd = col & 63;
      const float bvv = bias[col];
#pragma unroll
      for (int r = 0; r < 4; r++) {
        const int row = row0 + wrow + mi * 16 + rb + r;
        const int b = row >> 11, s = row & (S_ - 1);
        const float val = acc[mi][ni][r] + bvv;
        if (wsel == 0)
          Qh[(((size_t)(b * H_ + h)) * S_ + s) * HD_ + hd] = (bf16)(val * 0.125f);
        else if (wsel == 1)
          Kh[(((size_t)(b * H_ + h)) * S_ + s) * HD_ + hd] = (bf16)val;
        else
          Vt[(((size_t)(b * H_ + h)) * HD_ + hd) * S_ + s] = (bf16)val;
      }
    }
  }
}

// out = X(bf16) @ Wo_b^T + bias, fp32 out [4096][1024]. 64x256 tile, 8 waves, BK=64.
__global__ __launch_bounds__(512, 4) void out_gemm(
    const bf16* __restrict__ X, const bf16* __restrict__ W,
    const float* __restrict__ bias, float* __restrict__ Y) {
  __shared__ bf16 lA[64][64];    // gl16, source chunk-swizzled
  __shared__ bf16 lB[256][64];   // gl16, source chunk-swizzled
  const int tid = threadIdx.x, lane = tid & 63, wave = tid >> 6;
  const int row0 = blockIdx.x * 64, col0 = blockIdx.y * 256;
  const int lr = lane & 15, g = lane >> 4, lk = g * 8;
  const int wrow = (wave >> 2) * 32, wcol = (wave & 3) * 64;
  const int csw = ((lane & 7) ^ ((lane >> 3) & 7)) * 8;

  const bf16* Ap = X + (size_t)(row0 + wave * 8 + (lane >> 3)) * D_ + csw;
  const bf16* Wp = W + (size_t)(col0 + wave * 32 + (lane >> 3)) * D_ + csw;
  bf16* lAw = &lA[wave * 8][0];
  bf16* lBw = &lB[wave * 32][0];

  f32x4 acc[2][4] = {};
  for (int kk = 0; kk < D_; kk += 64) {
    __syncthreads();
    gl16(Ap + kk, lAw);
#pragma unroll
    for (int i = 0; i < 4; i++)
      gl16(Wp + (size_t)i * 8 * D_ + kk, lBw + i * 8 * 64);
    __syncthreads();

#pragma unroll
    for (int kd = 0; kd < 2; kd++) {
      s16x8 af[2], bfr[4];
#pragma unroll
      for (int mi = 0; mi < 2; mi++)
        af[mi] = *(const s16x8*)((const bf16*)lA +
                   (size_t)(wrow + mi * 16 + lr) * 64 +
                   (((4 * kd + g) ^ (lr & 7)) * 8));
#pragma unroll
      for (int ni = 0; ni < 4; ni++)
        bfr[ni] = *(const s16x8*)((const bf16*)lB +
                    (size_t)(wcol + ni * 16 + lr) * 64 +
                    (((4 * kd + g) ^ (lr & 7)) * 8));
#pragma unroll
      for (int mi = 0; mi < 2; mi++)
#pragma unroll
        for (int ni = 0; ni < 4; ni++)
          acc[mi][ni] = mfma16(af[mi], bfr[ni], acc[mi][ni]);
    }
  }

  const int rb = g * 4;
#pragma unroll
  for (int mi = 0; mi < 2; mi++) {
#pragma unroll
    for (int ni = 0; ni < 4; ni++) {
      const int col = col0 + wcol + ni * 16 + lr;
      const float bvv = bias[col];
#pragma unroll
      for (int r = 0; r < 4; r++) {
        const int row = row0 + wrow + mi * 16 + rb + r;
        Y[(size_t)row * D_ + col] = acc[mi][ni][r] + bvv;
      }
    }
  }
}

// Causal flash attention, swapped-QK^T softmax (col=q -> 2 shuffles/row-reduce).
// Qh/Kh: [bh][S][HD] bf16 (Q pre-scaled), Vt: [bh][HD][S] bf16. Out: [B*S][D] bf16.
__global__ __launch_bounds__(256) void attn_fwd(
    const bf16* __restrict__ Qh, const bf16* __restrict__ Kh,
    const bf16* __restrict__ Vt, bf16* __restrict__ attnO) {
  __shared__ bf16 k_lds[64][72];
  __shared__ bf16 vt_lds[64][72];
  __shared__ bf16 p_lds[4][32][72];
  __shared__ float red_lds[4][32];

  const int tid = threadIdx.x;
  const int lane = tid & 63, wave = tid >> 6;
  const int lr = lane & 15, g = lane >> 4, lk = g * 8, rb = g * 4;

  const int bidx = blockIdx.x;        // 512 blocks
  const int qb = 15 - (bidx >> 5);    // longest-first
  const int bh = bidx & 31;
  const int bb = bh >> 4, hh = bh & 15;
  const int q0w = qb * 128 + wave * 32;

  const bf16* Q = Qh + (size_t)bh * S_ * HD_;
  const bf16* K = Kh + (size_t)bh * S_ * HD_;
  const bf16* Vp = Vt + (size_t)bh * HD_ * S_;

  s16x8 qf[2][2];
#pragma unroll
  for (int qfi = 0; qfi < 2; qfi++)
#pragma unroll
    for (int kd = 0; kd < 2; kd++)
      qf[qfi][kd] = *(const s16x8*)(Q + (size_t)(q0w + qfi * 16 + lr) * HD_ + kd * 32 + lk);

  f32x4 o[2][4] = {};
  float m_run[2] = {-INFINITY, -INFINITY};
  float l_run[2] = {0.0f, 0.0f};

  const int srow = tid >> 2, d0 = (tid & 3) << 4;
  const int ntiles = qb * 2 + 2;

  s16x8 kr0, kr1, vr0, vr1;
  {
    const bf16* kp = K + (size_t)srow * HD_ + d0;
    kr0 = *(const s16x8*)kp;
    kr1 = *(const s16x8*)(kp + 8);
    const bf16* vp = Vp + (size_t)srow * S_ + d0;
    vr0 = *(const s16x8*)vp;
    vr1 = *(const s16x8*)(vp + 8);
  }

  for (int t = 0; t < ntiles; t++) {
    const int k0 = t * 64;
    __syncthreads();
    *(s16x8*)&k_lds[srow][d0] = kr0;
    *(s16x8*)&k_lds[srow][d0 + 8] = kr1;
    *(s16x8*)&vt_lds[srow][d0] = vr0;
    *(s16x8*)&vt_lds[srow][d0 + 8] = vr1;
    __syncthreads();
    if (t + 1 < ntiles) {
      const int kn = k0 + 64;
      const bf16* kp = K + (size_t)(kn + srow) * HD_ + d0;
      kr0 = *(const s16x8*)kp;
      kr1 = *(const s16x8*)(kp + 8);
      const bf16* vp = Vp + (size_t)srow * S_ + kn + d0;
      vr0 = *(const s16x8*)vp;
      vr1 = *(const s16x8*)(vp + 8);
    }

    if (k0 <= q0w + 31) {
      const bool doMask = (k0 + 63 > q0w);
      s16x8 kfr[4][2];
#pragma unroll
      for (int kf = 0; kf < 4; kf++)
#pragma unroll
        for (int kd = 0; kd < 2; kd++)
          kfr[kf][kd] = *(const s16x8*)&k_lds[kf * 16 + lr][kd * 32 + lk];
      f32x4 s[4][2];
#pragma unroll
      for (int kf = 0; kf < 4; kf++)
#pragma unroll
        for (int qfi = 0; qfi < 2; qfi++) s[kf][qfi] = (f32x4){0.f, 0.f, 0.f, 0.f};
      __builtin_amdgcn_s_setprio(1);
#pragma unroll
      for (int kf = 0; kf < 4; kf++)
#pragma unroll
        for (int qfi = 0; qfi < 2; qfi++)
#pragma unroll
          for (int kd = 0; kd < 2; kd++)
            s[kf][qfi] = mfma16(kfr[kf][kd], qf[qfi][kd], s[kf][qfi]);
      __builtin_amdgcn_s_setprio(0);

#pragma unroll
      for (int qfi = 0; qfi < 2; qfi++) {
        const int qg = q0w + qfi * 16 + lr;
        if (doMask) {
#pragma unroll
          for (int kf = 0; kf < 4; kf++)
#pragma unroll
            for (int r = 0; r < 4; r++)
              if (k0 + kf * 16 + rb + r > qg) s[kf][qfi][r] = -INFINITY;
        }
        float mx = fmaxf(fmaxf(s[0][qfi][0], s[0][qfi][1]), fmaxf(s[0][qfi][2], s[0][qfi][3]));
#pragma unroll
        for (int kf = 1; kf < 4; kf++)
          mx = fmaxf(mx, fmaxf(fmaxf(s[kf][qfi][0], s[kf][qfi][1]),
                               fmaxf(s[kf][qfi][2], s[kf][qfi][3])));
        mx = fmaxf(mx, __shfl_xor(mx, 16));
        mx = fmaxf(mx, __shfl_xor(mx, 32));
        const float mo = m_run[qfi];
        const float mn = fmaxf(mo, mx);
        const float corr = exp2f((mo - mn) * 1.44269504f);
        float ps = 0.0f;
#pragma unroll
        for (int kf = 0; kf < 4; kf++)
#pragma unroll
          for (int r = 0; r < 4; r++) {
            const float p = exp2f((s[kf][qfi][r] - mn) * 1.44269504f);
            s[kf][qfi][r] = p;
            ps += p;
          }
        ps += __shfl_xor(ps, 16);
        ps += __shfl_xor(ps, 32);
        l_run[qfi] = l_run[qfi] * corr + ps;
        m_run[qfi] = mn;
        if (g == 0) red_lds[wave][qfi * 16 + lr] = corr;
#pragma unroll
        for (int kf = 0; kf < 4; kf++)
#pragma unroll
          for (int rp = 0; rp < 2; rp++) {
            unsigned int lo = (unsigned int)__builtin_bit_cast(
                unsigned short, (bf16)s[kf][qfi][2 * rp]);
            unsigned int hi = (unsigned int)__builtin_bit_cast(
                unsigned short, (bf16)s[kf][qfi][2 * rp + 1]);
            *(unsigned int*)&p_lds[wave][qfi * 16 + lr][kf * 16 + rb + 2 * rp] =
                lo | (hi << 16);
          }
      }
#pragma unroll
      for (int rf = 0; rf < 2; rf++) {
        f32x4 c4 = *(const f32x4*)&red_lds[wave][rf * 16 + rb];
#pragma unroll
        for (int df = 0; df < 4; df++)
#pragma unroll
          for (int r = 0; r < 4; r++) o[rf][df][r] *= c4[r];
      }
      s16x8 vfr[4][2];
#pragma unroll
      for (int df = 0; df < 4; df++)
#pragma unroll
        for (int kk = 0; kk < 2; kk++)
          vfr[df][kk] = *(const s16x8*)&vt_lds[df * 16 + lr][kk * 32 + lk];
      __builtin_amdgcn_s_setprio(1);
#pragma unroll
      for (int rf = 0; rf < 2; rf++) {
        s16x8 pa[2];
#pragma unroll
        for (int kk = 0; kk < 2; kk++)
          pa[kk] = *(const s16x8*)&p_lds[wave][rf * 16 + lr][kk * 32 + lk];
#pragma unroll
        for (int df = 0; df < 4; df++)
#pragma unroll
          for (int kk = 0; kk < 2; kk++)
            o[rf][df] = mfma16(pa[kk], vfr[df][kk], o[rf][df]);
      }
      __builtin_amdgcn_s_setprio(0);
    }
  }

  if (g == 0) {
    red_lds[wave][lr] = l_run[0];
    red_lds[wave][16 + lr] = l_run[1];
  }
#pragma unroll
  for (int rf = 0; rf < 2; rf++) {
    f32x4 l4 = *(const f32x4*)&red_lds[wave][rf * 16 + rb];
    float inv[4];
#pragma unroll
    for (int r = 0; r < 4; r++) inv[r] = 1.0f / l4[r];
#pragma unroll
    for (int df = 0; df < 4; df++)
#pragma unroll
      for (int r = 0; r < 4; r++) {
        const int srw = q0w + rf * 16 + rb + r;
        const int dcol = df * 16 + lr;
        attnO[((size_t)(bb * S_ + srw)) * D_ + hh * HD_ + dcol] =
            (bf16)(o[rf][df][r] * inv[r]);
      }
  }
}

extern "C" void kernel_launch(void* const* d_in, const int* in_sizes, int n_in,
                              void* d_out, int out_size, void* d_ws, size_t ws_size,
                              hipStream_t stream) {
  const float* q  = (const float*)d_in[0];
  const float* k  = (const float*)d_in[1];
  const float* v  = (const float*)d_in[2];
  const float* Wq = (const float*)d_in[4];
  const float* bq = (const float*)d_in[5];
  const float* Wk = (const float*)d_in[6];
  const float* bk = (const float*)d_in[7];
  const float* Wv = (const float*)d_in[8];
  const float* bv = (const float*)d_in[9];
  const float* Wo = (const float*)d_in[10];
  const float* bo = (const float*)d_in[11];
  float* out = (float*)d_out;

  // 32 MB workspace layout (proven safe):
  //   [0,8M)   Qh     [8M,16M) Kh     [16M,24M) Vt
  //   [24M,30M) Wq_b|Wk_b|Wv_b (consumed by qkv_gemm)
  //   [24M,32M) attnB (reuses weight region after qkv_gemm — stream-ordered)
  //   [0,2M)    Wo_b  (reuses Qh region after attn_fwd — stream-ordered)
  const size_t NE = (size_t)B_ * S_ * D_;
  bf16* Qh    = (bf16*)d_ws;
  bf16* Kh    = Qh + NE;
  bf16* Vt    = Kh + NE;
  bf16* WbQKV = Vt + NE;
  bf16* attnB = Vt + NE;
  bf16* WoB   = (bf16*)d_ws;

  cvt_w<<<dim3(512, 3), 256, 0, stream>>>(Wq, Wk, Wv, WbQKV);
  qkv_gemm<<<dim3(32, 12), 512, 0, stream>>>(q, k, v, WbQKV, bq, bk, bv, Qh, Kh, Vt);
  attn_fwd<<<512, 256, 0, stream>>>(Qh, Kh, Vt, attnB);
  cvt_w1<<<512, 256, 0, stream>>>(Wo, WoB);
  out_gemm<<<dim3(64, 4), 512, 0, stream>>>(attnB, WoB, bo, out);
}